// Round 10
// baseline (65.674 us; speedup 1.0000x reference)
//
#include <hip/hip_runtime.h>

#define T 16
#define E 30
#define H 50
#define VOCAB 100
#define ROWS 208        // 13 row-tiles of 16; rows interleaved r = 4*unit + gate
#define K1 1.44269504089f   // log2(e)
#define K2 2.88539008178f   // 2*log2(e)
#define NTILE 13

typedef _Float16 v8hf __attribute__((ext_vector_type(8)));
typedef float v4f __attribute__((ext_vector_type(4)));

extern "C" __device__ float __ocml_native_exp2_f32(float);
__device__ __forceinline__ float e2(float x)   { return __ocml_native_exp2_f32(x); }
__device__ __forceinline__ float rcpf(float x) { return __builtin_amdgcn_rcpf(x); }

// tbl[dir][v][r], r = 4*unit + gate (i,f,g,o), orig row = gate*50+unit.
// Rows pre-scaled: i/f/o by -log2e (sigmoid = rcp(1+exp2(x))), g by 2*log2e.
__global__ void build_tbl(const float* __restrict__ emb,
                          const float* __restrict__ w_ih,
                          const float* __restrict__ b_ih,
                          const float* __restrict__ b_hh,
                          float* __restrict__ tbl) {
    int idx = blockIdx.x * blockDim.x + threadIdx.x;
    if (idx >= VOCAB * ROWS) return;
    int v = idx / ROWS, r = idx % ROWS;
    float s = 0.f;
    if (r < 4 * H) {
        int orig = (r & 3) * H + (r >> 2);
        s = b_ih[orig] + b_hh[orig];
        const float* er = emb + v * E;
        const float* wr = w_ih + orig * E;
#pragma unroll
        for (int e = 0; e < E; ++e) s += er[e] * wr[e];
        s *= ((r & 3) == 2) ? K2 : -K1;
    }
    tbl[idx] = s;
}

// One wave = one 16-seq group, all 13 tiles, zero barriers.
// h LDS layout READER-packed: hbuf[wave][seg][lane][8] fp16 — B-fragment is
// one conflict-free ds_read_b128 at lane*16; writers scatter b16.
__global__ __launch_bounds__(256, 2) void lstm_mfma(
    const int* __restrict__ ids,     // [NSEQ, T]
    const float* __restrict__ tbl,   // [2][VOCAB][ROWS]
    const float* __restrict__ whh_f, // [200][50]
    const float* __restrict__ whh_r, // [200][50]
    float* __restrict__ out)         // [NSEQ, 100]
{
    __shared__ _Float16 hbuf[4][2][64][8];   // 8 KB: [group][seg][lane][8]

    const int tid = threadIdx.x;
    const int lane = tid & 63;
    const int wave = tid >> 6;
    const int l15 = lane & 15;       // seq within group / C col
    const int lg = lane >> 4;        // k-/row-group
    const int b = blockIdx.x;
    const int dir = b >> 8;          // 512 blocks: 0..255 fwd, 256..511 rev
    const int seq = (b & 255) * 64 + wave * 16 + l15;

    const float* __restrict__ whh = dir ? whh_r : whh_f;
    const float* __restrict__ tb  = tbl + dir * (VOCAB * ROWS);
    const int* __restrict__ myids = ids + seq * T;

    _Float16* hb = &hbuf[wave][0][0][0];   // 1024 halves (seg stride 512)

    // zero own group's buffer (wave-private: no barrier needed anywhere)
    {
        int4* z = (int4*)hb;
        int4 zero; zero.x = zero.y = zero.z = zero.w = 0;
        z[lane] = zero;
        z[lane + 64] = zero;
    }

    // ragged length -> capture step (per lane's own sequence)
    int capt;
    {
        const int4* q = (const int4*)myids;
        int4 a0 = q[0], a1 = q[1], a2 = q[2], a3 = q[3];
        int len = (a0.x != 0) + (a0.y != 0) + (a0.z != 0) + (a0.w != 0)
                + (a1.x != 0) + (a1.y != 0) + (a1.z != 0) + (a1.w != 0)
                + (a2.x != 0) + (a2.y != 0) + (a2.z != 0) + (a2.w != 0)
                + (a3.x != 0) + (a3.y != 0) + (a3.z != 0) + (a3.w != 0);
        capt = dir ? (T - 1) : ((len > 1) ? (len - 1) : 0);
    }

    // A-fragments (pre-scaled fp16 W) resident for the whole kernel.
    v8hf afrag[NTILE][2];
#pragma unroll
    for (int i = 0; i < NTILE; ++i) {
        const int r = i * 16 + l15;
        const bool vr = (r < 4 * H);
        const int orig = vr ? ((r & 3) * H + (r >> 2)) : 0;
        const float sc = ((r & 3) == 2) ? K2 : -K1;
#pragma unroll
        for (int kh = 0; kh < 2; ++kh) {
            v8hf af;
#pragma unroll
            for (int j = 0; j < 8; ++j) {
                const int k = kh * 32 + lg * 8 + j;
                af[j] = (_Float16)((vr && k < H) ? sc * whh[orig * H + k] : 0.f);
            }
            afrag[i][kh] = af;
        }
    }

    // per-tile h write offsets (halfwords): unit u = i*4+lg ->
    // [u>>5][((u&31)>>3)*16 + l15][u&7]
    unsigned wa[NTILE];
#pragma unroll
    for (int i = 0; i < NTILE; ++i) {
        const int u = i * 4 + lg;
        wa[i] = ((u >> 5) << 9) + (((u & 31) >> 3) << 7) + (l15 << 3) + (u & 7);
    }
    const _Float16* rb0 = hb + lane * 8;          // seg 0 B-frag
    const _Float16* rb1 = hb + 512 + lane * 8;    // seg 1 B-frag

    float cs[NTILE], hcap[NTILE];
#pragma unroll
    for (int i = 0; i < NTILE; ++i) { cs[i] = 0.f; hcap[i] = 0.f; }

    // prefetch tv for t=0
    v4f tv[NTILE];
    {
        const int id0 = myids[dir ? (T - 1) : 0];
        const float* __restrict__ trow = tb + id0 * ROWS;
#pragma unroll
        for (int i = 0; i < NTILE; ++i)
            tv[i] = *(const v4f*)(trow + i * 16 + lg * 4);
    }

#pragma unroll 1   // keep the t-loop body ~4 KB: fits I$; 13-tile ILP inside
    for (int t = 0; t < T; ++t) {
        // id for step t+1 (issued early; feeds the in-flight prefetch)
        int tn = dir ? (T - 2 - t) : (t + 1);
        if (t == T - 1) tn = dir ? 0 : (T - 1);    // dummy valid index
        const int id_next = myids[tn];
        const float* __restrict__ trow_n = tb + id_next * ROWS;

        // B-fragments: previous step's h (conflict-free b128 reads)
        v8hf bh0 = *(const v8hf*)rb0;
        v8hf bh1 = *(const v8hf*)rb1;

        const bool cap = (t == capt);

#pragma unroll
        for (int i = 0; i < NTILE; ++i) {
            v4f c = __builtin_amdgcn_mfma_f32_16x16x32_f16(afrag[i][0], bh0, tv[i], 0, 0, 0);
            c = __builtin_amdgcn_mfma_f32_16x16x32_f16(afrag[i][1], bh1, c, 0, 0, 0);
            tv[i] = *(const v4f*)(trow_n + i * 16 + lg * 4);   // prefetch t+1

            // pre-scaled gates: ei=2^(-K1 xi) etc, eg=e^(2 xg), cs = K2*c.
            // Combined-denominator LSTM update: 5 exp2 + 2 rcp per unit.
            float ei = e2(c[0]);
            float ef = e2(c[1]);
            float eg = e2(c[2]);
            float eo = e2(c[3]);
            float ai  = 1.f + ei;
            float bf  = 1.f + ef;
            float gp  = eg + 1.f;
            float gm2 = fmaf(K2, eg, -K2);           // K2*(eg-1)
            float num = fmaf(cs[i] * ai, gp, gm2 * bf);
            float rD  = rcpf(ai * bf * gp);
            float cn  = num * rD;                     // cs' = K2 * c_new
            cs[i] = cn;
            float ec  = e2(cn);                       // e^(2 c_new)
            float em  = ec - 1.f;
            float ep  = ec + 1.f;
            float eo1 = 1.f + eo;
            float hn  = em * rcpf(eo1 * ep);          // o * tanh(c_new)

            if (i < 12 || lg < 2) {                   // unit u = i*4+lg < 50
                hb[wa[i]] = (_Float16)hn;
                hcap[i] = cap ? hn : hcap[i];
            }
        }
    }

#pragma unroll
    for (int i = 0; i < NTILE; ++i) {
        const int u = i * 4 + lg;
        if (u < H) out[seq * 100 + dir * H + u] = hcap[i];
    }
}

extern "C" void kernel_launch(void* const* d_in, const int* in_sizes, int n_in,
                              void* d_out, int out_size, void* d_ws, size_t ws_size,
                              hipStream_t stream) {
    const int*   char_ids = (const int*)d_in[0];
    const float* emb      = (const float*)d_in[1];
    const float* w_ih_f   = (const float*)d_in[2];
    const float* w_hh_f   = (const float*)d_in[3];
    const float* b_ih_f   = (const float*)d_in[4];
    const float* b_hh_f   = (const float*)d_in[5];
    const float* w_ih_r   = (const float*)d_in[6];
    const float* w_hh_r   = (const float*)d_in[7];
    const float* b_ih_r   = (const float*)d_in[8];
    const float* b_hh_r   = (const float*)d_in[9];
    float* out = (float*)d_out;
    float* tbl = (float*)d_ws; // [2][VOCAB][ROWS] f32 = 166.4 KB

    const int nt = VOCAB * ROWS; // 20800
    build_tbl<<<(nt + 255) / 256, 256, 0, stream>>>(emb, w_ih_f, b_ih_f, b_hh_f, tbl);
    build_tbl<<<(nt + 255) / 256, 256, 0, stream>>>(emb, w_ih_r, b_ih_r, b_hh_r, tbl + nt);
    // 512 blocks: 256 per direction; block = 4 independent 16-seq waves
    lstm_mfma<<<512, 256, 0, stream>>>(char_ids, tbl, w_hh_f, w_hh_r, out);
}